// Round 2
// baseline (5761.218 us; speedup 1.0000x reference)
//
#include <hip/hip_runtime.h>

#define B_ 32
#define C_ 512
#define N_ 4096
#define T_ 72
#define K_ 64
#define EPSF 1e-12f

// ---------------------------------------------------------------------------
// block (256) sum; result valid on thread 0 only.
// ---------------------------------------------------------------------------
__device__ __forceinline__ float block_reduce_sum_256(float v) {
    #pragma unroll
    for (int o = 32; o > 0; o >>= 1) v += __shfl_down(v, o, 64);
    __shared__ float w[4];
    const int lane = threadIdx.x & 63, wid = threadIdx.x >> 6;
    if (lane == 0) w[wid] = v;
    __syncthreads();
    float r = 0.f;
    if (threadIdx.x == 0) r = w[0] + w[1] + w[2] + w[3];
    return r;
}

// ---------------------------------------------------------------------------
// Kernel 1: inv_norm[b,n] = 1/max(||x[b,:,n]||,eps).
// grid (N/64, B), block 256: 4 c-partitions x 64 n. 2048 blocks -> 32 waves/CU.
// Memory-bound: reads x exactly once (256 MB).
// ---------------------------------------------------------------------------
__global__ __launch_bounds__(256) void k_norm(
    const float* __restrict__ x, float* __restrict__ inv_norm)
{
    const int nn = threadIdx.x & 63, cp = threadIdx.x >> 6;
    const int n  = blockIdx.x * 64 + nn;
    const int b  = blockIdx.y;
    const float* xb = x + (size_t)b * C_ * N_ + (size_t)(cp * 128) * N_ + n;

    float ss = 0.f;
    #pragma unroll 8
    for (int c = 0; c < 128; ++c) {
        float v = xb[(size_t)c * N_];
        ss = fmaf(v, v, ss);
    }
    __shared__ float red[4][64];
    red[cp][nn] = ss;
    __syncthreads();
    if (cp == 0) {
        const float tot = red[0][nn] + red[1][nn] + red[2][nn] + red[3][nn];
        inv_norm[(size_t)b * N_ + n] = 1.0f / fmaxf(sqrtf(tot), EPSF);
    }
}

// ---------------------------------------------------------------------------
// Kernel 2: logits/softmax/assign. Block 512 = 2 c-halves x 256 n.
// Each thread accumulates 72 partial logits over 256 channels; halves are
// combined through a k-chunked LDS exchange (24k x 256n = 24 KB -> 2 blocks/CU,
// 16 waves/CU). Waves 4..7 are half=1 (uniform branches).
// ---------------------------------------------------------------------------
__global__ __launch_bounds__(512, 4) void k_assign(
    const float* __restrict__ x, const float* __restrict__ conv_w,
    const float* __restrict__ conv_b, const float* __restrict__ inv_norm,
    float* __restrict__ assign)
{
    __shared__ float xch[24][256];

    const int t    = threadIdx.x;
    const int tn   = t & 255;
    const int half = t >> 8;            // wave-uniform
    const int n    = blockIdx.x * 256 + tn;
    const int b    = blockIdx.y;

    const float inv = inv_norm[(size_t)b * N_ + n];
    const float* xb = x + (size_t)b * C_ * N_ + (size_t)(half * 256) * N_ + n;
    const float* wb = conv_w + half * 256;   // conv_w[k*C + half*256 + c]

    float lg[T_];
    #pragma unroll
    for (int k = 0; k < T_; ++k) lg[k] = 0.f;

    #pragma unroll 2
    for (int c = 0; c < 256; ++c) {
        const float xv = xb[(size_t)c * N_] * inv;
        #pragma unroll
        for (int k = 0; k < T_; ++k)
            lg[k] = fmaf(wb[k * C_ + c], xv, lg[k]);
    }

    // combine halves, 24 clusters at a time
    #pragma unroll
    for (int r = 0; r < 3; ++r) {
        if (half == 1) {
            #pragma unroll
            for (int j = 0; j < 24; ++j) xch[j][tn] = lg[r * 24 + j];
        }
        __syncthreads();
        if (half == 0) {
            #pragma unroll
            for (int j = 0; j < 24; ++j) lg[r * 24 + j] += xch[j][tn];
        }
        __syncthreads();
    }

    if (half == 0) {
        #pragma unroll
        for (int k = 0; k < T_; ++k) lg[k] += conv_b[k];
        float m = lg[0];
        #pragma unroll
        for (int k = 1; k < T_; ++k) m = fmaxf(m, lg[k]);
        float s = 0.f;
        #pragma unroll
        for (int k = 0; k < T_; ++k) {
            lg[k] = __expf(lg[k] - m);
            s += lg[k];
        }
        const float rs = 1.0f / s;
        float* ab = assign + (size_t)b * K_ * N_ + n;
        #pragma unroll
        for (int k = 0; k < K_; ++k) ab[(size_t)k * N_] = lg[k] * rs;
    }
}

// ---------------------------------------------------------------------------
// Kernel 3: mass[b,k] = sum_n assign.  grid (K, B), block 256.
// ---------------------------------------------------------------------------
__global__ __launch_bounds__(256) void k_mass(
    const float* __restrict__ assign, float* __restrict__ mass)
{
    const int k = blockIdx.x, b = blockIdx.y;
    const float* p = assign + ((size_t)b * K_ + k) * N_;
    float s = 0.f;
    #pragma unroll 4
    for (int i = threadIdx.x; i < N_; i += 256) s += p[i];
    const float tot = block_reduce_sum_256(s);
    if (threadIdx.x == 0) mass[b * K_ + k] = tot;
}

// ---------------------------------------------------------------------------
// Kernel 4: agg accumulation. Each block: 64k x 64c tile over a 1024-n chunk;
// fp32 atomicAdd into out. grid (C/64, 4, B) = 1024 blocks -> 16 waves/CU.
// LDS layout [row][nn+1]: staging writes stride-1; compute reads broadcast
// across 16 lanes, 4 distinct banks -> conflict-free (verified 0 last round).
// ---------------------------------------------------------------------------
#define TN 64
__global__ __launch_bounds__(256) void k_agg(
    const float* __restrict__ x, const float* __restrict__ assign,
    const float* __restrict__ inv_norm, float* __restrict__ out)
{
    __shared__ float lds_a[K_][TN + 1];
    __shared__ float lds_x[TN][TN + 1];

    const int b   = blockIdx.z;
    const int nc0 = blockIdx.y * 1024;
    const int c0  = blockIdx.x * TN;
    const int tid = threadIdx.x;
    const int ti = tid >> 4, tj = tid & 15;

    const float* ab = assign   + (size_t)b * K_ * N_;
    const float* xb = x        + (size_t)b * C_ * N_;
    const float* ib = inv_norm + (size_t)b * N_;

    float acc[4][4] = {};

    for (int n0 = nc0; n0 < nc0 + 1024; n0 += TN) {
        __syncthreads();
        #pragma unroll
        for (int i = 0; i < 16; ++i) {
            const int idx = tid + i * 256;          // 0..4095
            const int r = idx >> 6, nn = idx & 63;
            lds_a[r][nn] = ab[(size_t)r * N_ + n0 + nn];
            lds_x[r][nn] = xb[(size_t)(c0 + r) * N_ + n0 + nn] * ib[n0 + nn];
        }
        __syncthreads();

        #pragma unroll 8
        for (int nn = 0; nn < TN; ++nn) {
            float av[4], xv[4];
            #pragma unroll
            for (int i = 0; i < 4; ++i) av[i] = lds_a[ti * 4 + i][nn];
            #pragma unroll
            for (int j = 0; j < 4; ++j) xv[j] = lds_x[tj * 4 + j][nn];
            #pragma unroll
            for (int i = 0; i < 4; ++i)
                #pragma unroll
                for (int j = 0; j < 4; ++j)
                    acc[i][j] = fmaf(av[i], xv[j], acc[i][j]);
        }
    }

    float* ob = out + (size_t)b * (K_ * C_);
    #pragma unroll
    for (int i = 0; i < 4; ++i) {
        const int k = ti * 4 + i;
        #pragma unroll
        for (int j = 0; j < 4; ++j)
            atomicAdd(ob + (size_t)k * C_ + c0 + tj * 4 + j, acc[i][j]);
    }
}

// ---------------------------------------------------------------------------
// Kernel 5: per-(b,k) row norm of vlad = agg - centroid*mass (computed on the
// fly); accumulate sum of row-normalized sumsq into gsum[b]. grid (K,B).
// ---------------------------------------------------------------------------
__global__ __launch_bounds__(256) void k_rnorm(
    const float* __restrict__ agg, const float* __restrict__ centroids,
    const float* __restrict__ mass, float* __restrict__ rnorm,
    float* __restrict__ gsum)
{
    const int k = blockIdx.x, b = blockIdx.y;
    const float mk = mass[b * K_ + k];
    const float* p = agg + ((size_t)b * K_ + k) * C_;
    const float* cb = centroids + k * C_;
    float s = 0.f;
    #pragma unroll 2
    for (int i = threadIdx.x; i < C_; i += 256) {
        float v = fmaf(-cb[i], mk, p[i]);
        s = fmaf(v, v, s);
    }
    const float ss = block_reduce_sum_256(s);
    if (threadIdx.x == 0) {
        const float rn = fmaxf(sqrtf(ss), EPSF);
        rnorm[b * K_ + k] = rn;
        atomicAdd(gsum + b, ss / (rn * rn));
    }
}

// ---------------------------------------------------------------------------
// Kernel 6: out = (agg - centroid*mass) / (rnorm * gnorm), in place, float4.
// ---------------------------------------------------------------------------
__global__ __launch_bounds__(256) void k_final(
    float* __restrict__ out, const float* __restrict__ centroids,
    const float* __restrict__ mass, const float* __restrict__ rnorm,
    const float* __restrict__ gsum)
{
    const size_t t  = (size_t)blockIdx.x * 256 + threadIdx.x;
    const size_t i4 = t * 4;
    const int b = (int)(i4 >> 15);           // 64*512 per batch
    const int k = (int)((i4 >> 9) & 63);     // 512 per cluster
    const int c = (int)(i4 & 511);
    const float gn = fmaxf(sqrtf(gsum[b]), EPSF);
    const float sc = 1.0f / (rnorm[b * K_ + k] * gn);
    const float mk = mass[b * K_ + k];
    float4 v  = *(const float4*)(out + i4);
    float4 cv = *(const float4*)(centroids + k * C_ + c);
    v.x = fmaf(-cv.x, mk, v.x) * sc;
    v.y = fmaf(-cv.y, mk, v.y) * sc;
    v.z = fmaf(-cv.z, mk, v.z) * sc;
    v.w = fmaf(-cv.w, mk, v.w) * sc;
    *(float4*)(out + i4) = v;
}

// ---------------------------------------------------------------------------
extern "C" void kernel_launch(void* const* d_in, const int* in_sizes, int n_in,
                              void* d_out, int out_size, void* d_ws, size_t ws_size,
                              hipStream_t stream) {
    const float* x         = (const float*)d_in[0];
    const float* centroids = (const float*)d_in[1];
    const float* conv_w    = (const float*)d_in[2];
    const float* conv_b    = (const float*)d_in[3];
    // d_in[4..8] (ghost_weights, w1, b1, w2, b2) provably cancel in the
    // intra-cluster L2 norm (positive per-row scalars) -> unused.

    float* out = (float*)d_out;
    float* ws  = (float*)d_ws;

    float* assign   = ws;                                   // B*K*N
    float* inv_norm = assign + (size_t)B_ * K_ * N_;        // B*N
    float* mass     = inv_norm + (size_t)B_ * N_;           // B*K
    float* rnorm    = mass + B_ * K_;                       // B*K
    float* gsum     = rnorm + B_ * K_;                      // B

    hipMemsetAsync(gsum, 0, B_ * sizeof(float), stream);
    hipMemsetAsync(out, 0, (size_t)out_size * sizeof(float), stream);

    k_norm<<<dim3(N_ / 64, B_), 256, 0, stream>>>(x, inv_norm);
    k_assign<<<dim3(N_ / 256, B_), 512, 0, stream>>>(x, conv_w, conv_b,
                                                     inv_norm, assign);
    k_mass<<<dim3(K_, B_), 256, 0, stream>>>(assign, mass);
    k_agg<<<dim3(C_ / TN, 4, B_), 256, 0, stream>>>(x, assign, inv_norm, out);
    k_rnorm<<<dim3(K_, B_), 256, 0, stream>>>(out, centroids, mass, rnorm, gsum);
    k_final<<<(out_size / 4 + 255) / 256, 256, 0, stream>>>(out, centroids,
                                                            mass, rnorm, gsum);
}

// Round 3
// 543.394 us; speedup vs baseline: 10.6023x; 10.6023x over previous
//
#include <hip/hip_runtime.h>
#include <hip/hip_bf16.h>

#define B_ 32
#define C_ 512
#define N_ 4096
#define T_ 72
#define K_ 64
#define KP 80            // clusters padded to 5 MFMA m-tiles
#define EPSF 1e-12f

typedef unsigned short u16;
typedef unsigned int u32;
typedef __attribute__((ext_vector_type(8))) short bf16x8;
typedef __attribute__((ext_vector_type(4))) float f32x4;

__device__ __forceinline__ u16 f2bf(float v) {
    __hip_bfloat16 h = __float2bfloat16(v);   // RNE
    return *reinterpret_cast<u16*>(&h);
}

// ---------------------------------------------------------------------------
// Prep: W padded [80][512] -> bf16 (rows >=72 zero); bias padded (-1e30 pads
// so padded rows vanish in softmax).
// ---------------------------------------------------------------------------
__global__ __launch_bounds__(256) void k_prep(
    const float* __restrict__ conv_w, const float* __restrict__ conv_b,
    u16* __restrict__ Wp, float* __restrict__ bp)
{
    const int idx = blockIdx.x * 256 + threadIdx.x;
    if (idx < KP * C_) {
        const int k = idx >> 9, c = idx & (C_ - 1);
        Wp[idx] = f2bf(k < T_ ? conv_w[k * C_ + c] : 0.f);
    } else if (idx < KP * C_ + KP) {
        const int j = idx - KP * C_;
        bp[j] = (j < T_) ? conv_b[j] : -1e30f;
    }
}

// ---------------------------------------------------------------------------
// Assign: per block 64 n, one b. Single fp32 read of x computes sumsq (fp32)
// and stages unscaled bf16 x^T in LDS (c-contiguous). Logits via
// mfma_16x16x32_bf16 (M=80 clusters, N=16 n/wave, K=c in 2 chunks of 256).
// inv_norm applied POST-GEMM (linear). Softmax in C-layout regs; mass via
// wave-reduced atomics; stores a' = a*inv (bf16) for the agg GEMM.
// LDS ~36 KB -> 4 blocks/CU (16 waves). No big per-thread arrays -> no spill.
// ---------------------------------------------------------------------------
#define AN 64
#define ACH 256
__global__ __launch_bounds__(256) void k_assign(
    const float* __restrict__ x, const u16* __restrict__ Wp,
    const float* __restrict__ bp, u16* __restrict__ assignp,
    float* __restrict__ mass)
{
    __shared__ u16   xt[AN][264];   // pitch 264: 16B-aligned rows, quad-spread b128 reads
    __shared__ float red[AN][9];
    __shared__ float linv[AN];

    const int t  = threadIdx.x;
    const int b  = blockIdx.y;
    const int n0 = blockIdx.x * AN;

    const int np = t & 31;          // n-pair for staging
    const int cg = t >> 5;          // 0..7 c-group
    const float* xb = x + (size_t)b * C_ * N_ + n0 + 2 * np;

    const int lane = t & 63, w = t >> 6;
    const int q = lane >> 4, nl = lane & 15;

    f32x4 acc[5];
    #pragma unroll
    for (int mt = 0; mt < 5; ++mt) acc[mt] = (f32x4)0.f;

    float ss0 = 0.f, ss1 = 0.f;

    #pragma unroll 1
    for (int half = 0; half < 2; ++half) {
        const int cbase = half * ACH;
        // ---- stage chunk: fp32 load (coalesced float2), sumsq, cvt bf16 ----
        #pragma unroll 4
        for (int ci = 0; ci < 32; ++ci) {
            const int c = cg * 32 + ci;
            const float2 v = *(const float2*)(xb + (size_t)(cbase + c) * N_);
            ss0 = fmaf(v.x, v.x, ss0);
            ss1 = fmaf(v.y, v.y, ss1);
            xt[2 * np][c]     = f2bf(v.x);
            xt[2 * np + 1][c] = f2bf(v.y);
        }
        if (half == 1) {
            red[2 * np][cg]     = ss0;
            red[2 * np + 1][cg] = ss1;
        }
        __syncthreads();
        if (half == 1 && t < AN) {
            float s = 0.f;
            #pragma unroll
            for (int j = 0; j < 8; ++j) s += red[t][j];
            linv[t] = 1.0f / fmaxf(sqrtf(s), EPSF);
        }
        // ---- MFMA K-loop over this chunk ----
        const u16* wrow = Wp + (size_t)nl * C_ + cbase + q * 8;
        #pragma unroll
        for (int ks = 0; ks < ACH / 32; ++ks) {
            const bf16x8 bf = *(const bf16x8*)(&xt[16 * w + nl][ks * 32 + q * 8]);
            #pragma unroll
            for (int mt = 0; mt < 5; ++mt) {
                const bf16x8 af = *(const bf16x8*)(wrow + (size_t)(mt * 16) * C_ + ks * 32);
                acc[mt] = __builtin_amdgcn_mfma_f32_16x16x32_bf16(af, bf, acc[mt], 0, 0, 0);
            }
        }
        __syncthreads();
    }

    // ---- epilogue: C-layout D[row k = q*4+reg (+16*mt)][col n = nl] ----
    const float invn  = linv[16 * w + nl];
    const int   nglob = n0 + 16 * w + nl;

    float lg[5][4];
    #pragma unroll
    for (int mt = 0; mt < 5; ++mt)
        #pragma unroll
        for (int r = 0; r < 4; ++r)
            lg[mt][r] = acc[mt][r] * invn + bp[mt * 16 + q * 4 + r];

    float mx = -1e30f;
    #pragma unroll
    for (int mt = 0; mt < 5; ++mt)
        #pragma unroll
        for (int r = 0; r < 4; ++r) mx = fmaxf(mx, lg[mt][r]);
    mx = fmaxf(mx, __shfl_xor(mx, 16, 64));
    mx = fmaxf(mx, __shfl_xor(mx, 32, 64));

    float s = 0.f;
    #pragma unroll
    for (int mt = 0; mt < 5; ++mt)
        #pragma unroll
        for (int r = 0; r < 4; ++r) {
            lg[mt][r] = __expf(lg[mt][r] - mx);
            s += lg[mt][r];
        }
    s += __shfl_xor(s, 16, 64);
    s += __shfl_xor(s, 32, 64);
    const float rs = 1.0f / s;

    #pragma unroll
    for (int mt = 0; mt < 4; ++mt)          // real clusters only
        #pragma unroll
        for (int r = 0; r < 4; ++r) {
            const float a = lg[mt][r] * rs;
            float msum = a;
            msum += __shfl_xor(msum, 1, 64);
            msum += __shfl_xor(msum, 2, 64);
            msum += __shfl_xor(msum, 4, 64);
            msum += __shfl_xor(msum, 8, 64);
            const int k = mt * 16 + q * 4 + r;
            if (nl == 0) atomicAdd(&mass[b * K_ + k], msum);
            assignp[((size_t)b * K_ + k) * N_ + nglob] = f2bf(a * invn);
        }
}

// ---------------------------------------------------------------------------
// Agg: agg[k][c] = sum_n a'[k,n] * x_bf16[c,n].  M=64k, N=64c tile, K=n in 4
// chunks (fp32 atomicAdd into out). A from assignp (bf16, natural layout);
// B staged from fp32 x with on-the-fly cvt. 1024 blocks -> 4/CU.
// ---------------------------------------------------------------------------
#define GBK 64
#define NCH 4
__global__ __launch_bounds__(256) void k_agg(
    const float* __restrict__ x, const u16* __restrict__ assignp,
    float* __restrict__ out)
{
    __shared__ u16 At[K_][72];   // 64k x 64n, pitch 72: aligned + quad-spread
    __shared__ u16 Bt[K_][72];   // 64c x 64n

    const int t  = threadIdx.x;
    const int b  = blockIdx.z;
    const int nc0 = blockIdx.y * (N_ / NCH);
    const int c0  = blockIdx.x * 64;

    const int lane = t & 63, w = t >> 6;
    const int q = lane >> 4, nl = lane & 15;

    f32x4 acc[4];
    #pragma unroll
    for (int mt = 0; mt < 4; ++mt) acc[mt] = (f32x4)0.f;

    const u16*   ab = assignp + (size_t)b * K_ * N_;
    const float* xb = x + (size_t)b * C_ * N_;

    const int au = t & 7,  ar = t >> 3;   // A staging: 16B units
    const int bp2 = t & 31, bc = t >> 5;  // B staging: float2

    #pragma unroll 1
    for (int n0 = nc0; n0 < nc0 + N_ / NCH; n0 += GBK) {
        __syncthreads();
        #pragma unroll
        for (int p = 0; p < 2; ++p) {
            const int r = ar + 32 * p;
            *(uint4*)(&At[r][au * 8]) =
                *(const uint4*)(ab + (size_t)r * N_ + n0 + au * 8);
        }
        #pragma unroll
        for (int p = 0; p < 8; ++p) {
            const int c = bc + 8 * p;
            const float2 v = *(const float2*)(xb + (size_t)(c0 + c) * N_ + n0 + 2 * bp2);
            const u32 pk = (u32)f2bf(v.x) | ((u32)f2bf(v.y) << 16);
            *(u32*)(&Bt[c][2 * bp2]) = pk;
        }
        __syncthreads();
        #pragma unroll
        for (int kk = 0; kk < 2; ++kk) {
            const bf16x8 bf = *(const bf16x8*)(&Bt[16 * w + nl][kk * 32 + q * 8]);
            #pragma unroll
            for (int mt = 0; mt < 4; ++mt) {
                const bf16x8 af = *(const bf16x8*)(&At[mt * 16 + nl][kk * 32 + q * 8]);
                acc[mt] = __builtin_amdgcn_mfma_f32_16x16x32_bf16(af, bf, acc[mt], 0, 0, 0);
            }
        }
    }

    float* ob = out + (size_t)b * K_ * C_;
    const int c = c0 + 16 * w + nl;
    #pragma unroll
    for (int mt = 0; mt < 4; ++mt)
        #pragma unroll
        for (int r = 0; r < 4; ++r)
            atomicAdd(&ob[(size_t)(mt * 16 + q * 4 + r) * C_ + c], acc[mt][r]);
}

// ---------------------------------------------------------------------------
// Row norms + global norm (fp32 exact), unchanged from round 2.
// ---------------------------------------------------------------------------
__device__ __forceinline__ float block_reduce_sum_256(float v) {
    #pragma unroll
    for (int o = 32; o > 0; o >>= 1) v += __shfl_down(v, o, 64);
    __shared__ float wsh[4];
    const int lane = threadIdx.x & 63, wid = threadIdx.x >> 6;
    if (lane == 0) wsh[wid] = v;
    __syncthreads();
    float r = 0.f;
    if (threadIdx.x == 0) r = wsh[0] + wsh[1] + wsh[2] + wsh[3];
    return r;
}

__global__ __launch_bounds__(256) void k_rnorm(
    const float* __restrict__ agg, const float* __restrict__ centroids,
    const float* __restrict__ mass, float* __restrict__ rnorm,
    float* __restrict__ gsum)
{
    const int k = blockIdx.x, b = blockIdx.y;
    const float mk = mass[b * K_ + k];
    const float* p  = agg + ((size_t)b * K_ + k) * C_;
    const float* cb = centroids + k * C_;
    float s = 0.f;
    #pragma unroll 2
    for (int i = threadIdx.x; i < C_; i += 256) {
        const float v = fmaf(-cb[i], mk, p[i]);
        s = fmaf(v, v, s);
    }
    const float ss = block_reduce_sum_256(s);
    if (threadIdx.x == 0) {
        const float rn = fmaxf(sqrtf(ss), EPSF);
        rnorm[b * K_ + k] = rn;
        atomicAdd(gsum + b, ss / (rn * rn));
    }
}

__global__ __launch_bounds__(256) void k_final(
    float* __restrict__ out, const float* __restrict__ centroids,
    const float* __restrict__ mass, const float* __restrict__ rnorm,
    const float* __restrict__ gsum)
{
    const size_t i4 = ((size_t)blockIdx.x * 256 + threadIdx.x) * 4;
    const int b = (int)(i4 >> 15);
    const int k = (int)((i4 >> 9) & 63);
    const int c = (int)(i4 & 511);
    const float gn = fmaxf(sqrtf(gsum[b]), EPSF);
    const float sc = 1.0f / (rnorm[b * K_ + k] * gn);
    const float mk = mass[b * K_ + k];
    float4 v  = *(const float4*)(out + i4);
    const float4 cv = *(const float4*)(centroids + k * C_ + c);
    v.x = fmaf(-cv.x, mk, v.x) * sc;
    v.y = fmaf(-cv.y, mk, v.y) * sc;
    v.z = fmaf(-cv.z, mk, v.z) * sc;
    v.w = fmaf(-cv.w, mk, v.w) * sc;
    *(float4*)(out + i4) = v;
}

// ---------------------------------------------------------------------------
extern "C" void kernel_launch(void* const* d_in, const int* in_sizes, int n_in,
                              void* d_out, int out_size, void* d_ws, size_t ws_size,
                              hipStream_t stream) {
    const float* x         = (const float*)d_in[0];
    const float* centroids = (const float*)d_in[1];
    const float* conv_w    = (const float*)d_in[2];
    const float* conv_b    = (const float*)d_in[3];
    // d_in[4..8] (ghost_weights, w1, b1, w2, b2): positive per-row scalars
    // cancel inside the intra-cluster L2 norm; ghost rows dropped -> unused.

    float* out = (float*)d_out;
    char*  ws  = (char*)d_ws;

    u16*   assignp = (u16*)ws;                               // 16,777,216 B
    u16*   Wp      = (u16*)(ws + 16777216);                  // 81,920 B
    float* bpad    = (float*)(ws + 16777216 + 81920);        // 320 B
    float* mass    = (float*)(ws + 16777216 + 81920 + 320);  // 8 KB
    float* rnorm   = mass + B_ * K_;
    float* gsum    = rnorm + B_ * K_;

    hipMemsetAsync(mass, 0, B_ * K_ * sizeof(float), stream);
    hipMemsetAsync(gsum, 0, B_ * sizeof(float), stream);
    hipMemsetAsync(out, 0, (size_t)out_size * sizeof(float), stream);

    k_prep<<<dim3((KP * C_ + KP + 255) / 256), 256, 0, stream>>>(conv_w, conv_b, Wp, bpad);
    k_assign<<<dim3(N_ / AN, B_), 256, 0, stream>>>(x, Wp, bpad, assignp, mass);
    k_agg<<<dim3(C_ / 64, NCH, B_), 256, 0, stream>>>(x, assignp, out);
    k_rnorm<<<dim3(K_, B_), 256, 0, stream>>>(out, centroids, mass, rnorm, gsum);
    k_final<<<(out_size / 4 + 255) / 256, 256, 0, stream>>>(out, centroids, mass, rnorm, gsum);
}